// Round 4
// baseline (69.021 us; speedup 1.0000x reference)
//
#include <hip/hip_runtime.h>

#define B 512
#define D 256
#define NCLS 10
#define MARGIN 0.2f
#define THREADS 1024
#define NWAVES (THREADS / 64)   // 16 waves, 4/SIMD
#define ROWS 2
#define NBLOCKS (B / ROWS)      // 256 blocks = 1/CU
#define DT 32                   // D-slice per tile (floats)
#define NDT (D / DT)            // 8 tiles
#define TILE_FLOATS (B * DT)    // 16384 floats = 64 KB per buffer

typedef float f32x4 __attribute__((ext_vector_type(4)));

// v5 = v4 with anchors moved off the LDS pipe onto the scalar pipe.
//  - e-quarter is WAVE-UNIFORM (q = w&3; col-pairs g = (w>>2)*64 + lane), so
//    the anchor slice address is wave-uniform -> inline-asm s_load_dwordx4
//    (K$ / lgkmcnt path, NOT vmcnt -> cannot re-entangle the DMA pipeline).
//    FMAs use the anchor as the single legal SGPR operand. LDS read instrs
//    halve: 64 -> 32 b128 per thread (x-reads only; each staged element read
//    exactly once = minimal).
//  - rule-18 fence (lgkmcnt(0) + sched_barrier(0)) between s_loads and FMAs.
//  - staging unchanged (verified): global_load_lds dwordx4, linear LDS dest,
//    XOR placement swizzle on the per-lane GLOBAL source; LDS quad p holds
//    global (j=p>>3, e4=(p&7)^sj), sj=(j&7)^((j>>3)&7); read of (j,e4) at
//    quad 8j+(e4^sj). Per-8-lane-group quads are a permutation -> conflict-free.
__global__ __launch_bounds__(THREADS) void fused_loss_kernel(
    const float* __restrict__ F, const int* __restrict__ labels,
    float* __restrict__ out)
{
    __shared__ float  buf[2][TILE_FLOATS];   // 128 KB
    __shared__ float  pos_vals[ROWS][B + 4]; // +4: float4 tail pad
    __shared__ float  neg_vals[ROWS][B];
    __shared__ int    lbl[B];
    __shared__ int    cnt[ROWS][2];
    __shared__ int    hist[NCLS];
    __shared__ float  wred[NWAVES];
    __shared__ int    vred[NWAVES];

    const int t    = threadIdx.x;
    const int lane = t & 63;
    const int w    = t >> 6;
    const int i0   = blockIdx.x * ROWS;
    const int rq   = __builtin_amdgcn_readfirstlane(w & 3);  // wave-uniform quarter
    const int g    = ((w >> 2) << 6) + lane;  // col-pair index (0..255)
    const int j0   = 2 * g;
    const int j1   = 2 * g + 1;
    const int s0   = (j0 & 7) ^ ((j0 >> 3) & 7);
    const int s1   = (j1 & 7) ^ ((j1 >> 3) & 7);

    auto stage = [&](float* dstbase, int tile) {
#pragma unroll
        for (int k = 0; k < 4; ++k) {
            const int p  = (w << 8) + (k << 6) + lane;
            const int jj = p >> 3;
            const int e4 = (p & 7) ^ (jj & 7) ^ ((jj >> 3) & 7);
            const float* src = F + jj * D + tile * DT + (e4 << 2);
            float* dst = dstbase + (w << 10) + (k << 8);
            __builtin_amdgcn_global_load_lds(
                (const __attribute__((address_space(1))) void*)src,
                (__attribute__((address_space(3))) void*)dst, 16, 0, 0);
        }
    };

    if (t < B)        lbl[t] = labels[t];
    if (t < NCLS)     hist[t] = 0;
    if (t < ROWS * 2) ((int*)cnt)[t] = 0;
    stage(buf[0], 0);

    asm volatile("s_waitcnt lgkmcnt(0)" ::: "memory");
    __builtin_amdgcn_s_barrier();

    if (t < B) atomicAdd(&hist[lbl[t]], 1);  // 10-bin LDS histogram

    const uint64_t sbase =
        (uint64_t)(const void*)(F + (size_t)i0 * D + 8 * rq);

    float acc00 = 0.f, acc01 = 0.f, acc10 = 0.f, acc11 = 0.f; // acc[col][row]
    int cur = 0;
    for (int tile = 0; tile < NDT; ++tile) {
        if (tile + 1 < NDT) {
            stage(buf[cur ^ 1], tile + 1);               // prefetch next tile
            asm volatile("s_waitcnt vmcnt(4)" ::: "memory");  // this tile done
        } else {
            asm volatile("s_waitcnt vmcnt(0)" ::: "memory");
        }
        __builtin_amdgcn_s_barrier();        // all waves' DMA for cur landed
        __builtin_amdgcn_sched_barrier(0);

        const uint64_t sb = sbase + (uint64_t)(tile * DT * 4);
        f32x4 a00, a01, a10, a11;  // a<k><row>: row0 k0/k1, row1 k0/k1
        asm volatile("s_load_dwordx4 %0, %1, 0x0"   : "=s"(a00) : "s"(sb));
        asm volatile("s_load_dwordx4 %0, %1, 0x10"  : "=s"(a01) : "s"(sb));
        asm volatile("s_load_dwordx4 %0, %1, 0x400" : "=s"(a10) : "s"(sb));
        asm volatile("s_load_dwordx4 %0, %1, 0x410" : "=s"(a11) : "s"(sb));

        const float* bufc = buf[cur];
        const int e40 = 2 * rq;
        const int e41 = 2 * rq + 1;
        const float4 x00 = *(const float4*)&bufc[(j0 << 5) + ((e40 ^ s0) << 2)];
        const float4 x01 = *(const float4*)&bufc[(j0 << 5) + ((e41 ^ s0) << 2)];
        const float4 x10 = *(const float4*)&bufc[(j1 << 5) + ((e40 ^ s1) << 2)];
        const float4 x11 = *(const float4*)&bufc[(j1 << 5) + ((e41 ^ s1) << 2)];

        asm volatile("s_waitcnt lgkmcnt(0)" ::: "memory");  // s_loads + ds_reads
        __builtin_amdgcn_sched_barrier(0);                  // rule-18 fence

        acc00 = fmaf(a00.x, x00.x, acc00); acc00 = fmaf(a00.y, x00.y, acc00);
        acc00 = fmaf(a00.z, x00.z, acc00); acc00 = fmaf(a00.w, x00.w, acc00);
        acc01 = fmaf(a10.x, x00.x, acc01); acc01 = fmaf(a10.y, x00.y, acc01);
        acc01 = fmaf(a10.z, x00.z, acc01); acc01 = fmaf(a10.w, x00.w, acc01);
        acc10 = fmaf(a00.x, x10.x, acc10); acc10 = fmaf(a00.y, x10.y, acc10);
        acc10 = fmaf(a00.z, x10.z, acc10); acc10 = fmaf(a00.w, x10.w, acc10);
        acc11 = fmaf(a10.x, x10.x, acc11); acc11 = fmaf(a10.y, x10.y, acc11);
        acc11 = fmaf(a10.z, x10.z, acc11); acc11 = fmaf(a10.w, x10.w, acc11);

        acc00 = fmaf(a01.x, x01.x, acc00); acc00 = fmaf(a01.y, x01.y, acc00);
        acc00 = fmaf(a01.z, x01.z, acc00); acc00 = fmaf(a01.w, x01.w, acc00);
        acc01 = fmaf(a11.x, x01.x, acc01); acc01 = fmaf(a11.y, x01.y, acc01);
        acc01 = fmaf(a11.z, x01.z, acc01); acc01 = fmaf(a11.w, x01.w, acc01);
        acc10 = fmaf(a01.x, x11.x, acc10); acc10 = fmaf(a01.y, x11.y, acc10);
        acc10 = fmaf(a01.z, x11.z, acc10); acc10 = fmaf(a01.w, x11.w, acc10);
        acc11 = fmaf(a11.x, x11.x, acc11); acc11 = fmaf(a11.y, x11.y, acc11);
        acc11 = fmaf(a11.z, x11.z, acc11); acc11 = fmaf(a11.w, x11.w, acc11);

        __builtin_amdgcn_sched_barrier(0);   // keep reads+FMAs before barrier
        __builtin_amdgcn_s_barrier();        // cur safe to overwrite next iter
        cur ^= 1;
    }

    // 4-way partial combine via LDS aliased onto dead buf[0]
    float2* part = (float2*)buf[0];          // part[q*512 + j] = (row0, row1)
    part[(rq << 9) + j0] = make_float2(acc00, acc01);
    part[(rq << 9) + j1] = make_float2(acc10, acc11);
    __syncthreads();
    const int j = t & (B - 1);               // owned sim column
    const int h = t >> 9;                    // wave-uniform row select
    const float2 p0 = part[(0 << 9) + j];
    const float2 p1 = part[(1 << 9) + j];
    const float2 p2 = part[(2 << 9) + j];
    const float2 p3 = part[(3 << 9) + j];
    const float sv = h ? (p0.y + p1.y + p2.y + p3.y)
                       : (p0.x + p1.x + p2.x + p3.x);

    // num_valid: row j valid iff 2 <= c[l_j] <= B-1 (h=0 half counts)
    {
        bool valid = false;
        if (t < B) { const int c = hist[lbl[t]]; valid = (c >= 2) && (c <= B - 1); }
        const unsigned long long mv = __ballot(valid);
        if (lane == 0) vred[w] = __popcll(mv);
    }

    // ---- hinge phase: both rows concurrently (wave-half per row) ----
    const int r   = h;
    const int i_r = i0 + r;
    const int li  = lbl[i_r];
    {
        const bool active = (j != i_r);
        const bool ispos  = active && (lbl[j] == li);
        const bool isneg  = active && (lbl[j] != li);
        const unsigned long long mp = __ballot(ispos);
        const unsigned long long mn = __ballot(isneg);
        int basep = 0, basen = 0;
        if (lane == 0) {
            basep = atomicAdd(&cnt[r][0], __popcll(mp));
            basen = atomicAdd(&cnt[r][1], __popcll(mn));
        }
        basep = __shfl(basep, 0, 64);
        basen = __shfl(basen, 0, 64);
        const unsigned long long below = (1ull << lane) - 1ull;
        if (ispos) pos_vals[r][basep + __popcll(mp & below)] = sv;
        if (isneg) neg_vals[r][basen + __popcll(mn & below)] = sv;
    }
    __syncthreads();
    const int P = cnt[r][0], N = cnt[r][1];
    if (j < 4) pos_vals[r][P + j] = 1e30f;   // +INF pad -> relu clamps to 0
    __syncthreads();

    const float nv_t = (j < N) ? neg_vals[r][j] : -1e30f;
    float local = 0.f;
    for (int pi = 0; pi < P; pi += 4) {
        const float4 pv = *(const float4*)&pos_vals[r][pi];
        float v;
        v = nv_t - (pv.x - MARGIN); local += (v > 0.f) ? v : 0.f;
        v = nv_t - (pv.y - MARGIN); local += (v > 0.f) ? v : 0.f;
        v = nv_t - (pv.z - MARGIN); local += (v > 0.f) ? v : 0.f;
        v = nv_t - (pv.w - MARGIN); local += (v > 0.f) ? v : 0.f;
    }

#pragma unroll
    for (int off = 32; off > 0; off >>= 1)
        local += __shfl_down(local, off, 64);
    if (lane == 0) wred[w] = local;
    __syncthreads();
    if (t == 0) {
        float s = 0.f;
        int   nv = 0;
#pragma unroll
        for (int k = 0; k < NWAVES; ++k) { s += wred[k]; nv += vred[k]; }
        const int   clast = hist[lbl[B - 1]];
        const float denom = (float)nv * (float)(clast - 1) * (float)(B - clast);
        atomicAdd(out, (denom > 0.f) ? s / denom : 0.f);
    }
}

extern "C" void kernel_launch(void* const* d_in, const int* in_sizes, int n_in,
                              void* d_out, int out_size, void* d_ws, size_t ws_size,
                              hipStream_t stream) {
    const float* F      = (const float*)d_in[0];   // [512, 256] fp32
    const int*   labels = (const int*)d_in[1];     // [512] int32
    float* out = (float*)d_out;
    (void)d_ws; (void)ws_size;

    fused_loss_kernel<<<NBLOCKS, THREADS, 0, stream>>>(F, labels, out);
}

// Round 5
// 68.366 us; speedup vs baseline: 1.0096x; 1.0096x over previous
//
#include <hip/hip_runtime.h>

#define B 512
#define D 256
#define NCLS 10
#define MARGIN 0.2f
#define THREADS 1024
#define NWAVES (THREADS / 64)   // 16 waves, 4/SIMD
#define ROWS 2
#define NBLOCKS (B / ROWS)      // 256 blocks = 1/CU
#define DT 32                   // D-slice per tile (floats)
#define NDT (D / DT)            // 8 tiles
#define TILE_FLOATS (B * DT)    // 16384 floats = 64 KB per buffer

// v6 = revert to v4 (best measured: 67.38us). v5's s_load anchors regressed:
// the per-tile lgkmcnt(0) drained K$-latency s_loads on the critical path,
// while v4's fi[] anchor reads are 4-distinct-quad broadcasts (nearly free on
// the LDS data path). Kernel-side arithmetic: 128 b128-instr/CU/tile x 8 clk
// x 8 tiles ~= 3.4us = measured kernel time -> LDS-data-BW floor, staging
// fully hidden by the counted-vmcnt double buffer.
//  - anchors staged ONCE into LDS fi[2][256]; compute loop has ZERO global
//    VMEM -> s_waitcnt vmcnt(4) counts only the DMA prefetch.
//  - micro-tile: thread (g=t>>2, q=t&3) computes cols {2g,2g+1} x rows {0,1}
//    over e-quarter q: per k-step 2 x-reads + 2 anchor broadcasts feed 16
//    FMAs; partials combined 4-way via LDS aliased onto dead buf[0].
//  - staging: global_load_lds dwordx4, linear LDS dest, XOR placement swizzle
//    on the per-lane GLOBAL source; LDS quad p holds global (j=p>>3,
//    e4=(p&7)^sj), sj=(j&7)^((j>>3)&7); read of (j,e4) at quad 8j+(e4^sj).
//    Per-8-lane-group quads distinct -> conflict-free b128.
__global__ __launch_bounds__(THREADS) void fused_loss_kernel(
    const float* __restrict__ F, const int* __restrict__ labels,
    float* __restrict__ out)
{
    __shared__ float  buf[2][TILE_FLOATS];   // 128 KB
    __shared__ float  fi[ROWS][D];           // anchor rows (2 KB)
    __shared__ float  pos_vals[ROWS][B + 4]; // +4: float4 tail pad
    __shared__ float  neg_vals[ROWS][B];
    __shared__ int    lbl[B];
    __shared__ int    cnt[ROWS][2];
    __shared__ int    hist[NCLS];
    __shared__ float  wred[NWAVES];
    __shared__ int    vred[NWAVES];

    const int t    = threadIdx.x;
    const int lane = t & 63;
    const int w    = t >> 6;
    const int i0   = blockIdx.x * ROWS;
    const int q    = t & 3;                  // e-quarter within tile
    const int g    = t >> 2;                 // col-pair index (0..255)
    const int j0   = 2 * g;
    const int j1   = 2 * g + 1;
    const int s0   = (j0 & 7) ^ ((j0 >> 3) & 7);
    const int s1   = (j1 & 7) ^ ((j1 >> 3) & 7);

    // async DMA stage of one tile: 4096 quads, 4 per thread; dest wave-uniform
    // base + lane*16 (linear); source pre-swizzled per lane.
    auto stage = [&](float* dstbase, int tile) {
#pragma unroll
        for (int k = 0; k < 4; ++k) {
            const int p  = (w << 8) + (k << 6) + lane;
            const int jj = p >> 3;
            const int e4 = (p & 7) ^ (jj & 7) ^ ((jj >> 3) & 7);
            const float* src = F + jj * D + tile * DT + (e4 << 2);
            float* dst = dstbase + (w << 10) + (k << 8);
            __builtin_amdgcn_global_load_lds(
                (const __attribute__((address_space(1))) void*)src,
                (__attribute__((address_space(3))) void*)dst, 16, 0, 0);
        }
    };

    // LDS init writes + anchor staging, then kick off tile-0 DMA
    if (t < B)        lbl[t] = labels[t];
    if (t < NCLS)     hist[t] = 0;
    if (t < ROWS * 2) ((int*)cnt)[t] = 0;
    if (t < (ROWS * D) / 4)
        ((float4*)fi)[t] = ((const float4*)(F + (size_t)i0 * D))[t];
    stage(buf[0], 0);

    // drain LDS writes (one-time) but not the tile-0 DMA
    asm volatile("s_waitcnt lgkmcnt(0)" ::: "memory");
    __builtin_amdgcn_s_barrier();

    if (t < B) atomicAdd(&hist[lbl[t]], 1);  // 10-bin LDS histogram

    // ---- sim phase: 2-phase pipelined tiles, zero global VMEM in loop ----
    float acc00 = 0.f, acc01 = 0.f, acc10 = 0.f, acc11 = 0.f; // acc[c][r]
    int cur = 0;
    for (int tile = 0; tile < NDT; ++tile) {
        if (tile + 1 < NDT) {
            stage(buf[cur ^ 1], tile + 1);               // prefetch next tile
            asm volatile("s_waitcnt vmcnt(4)" ::: "memory");  // this tile done
        } else {
            asm volatile("s_waitcnt vmcnt(0)" ::: "memory");
        }
        __builtin_amdgcn_s_barrier();        // all waves' DMA for cur landed
        __builtin_amdgcn_sched_barrier(0);
        const float* bufc = buf[cur];
        const int dt = tile * DT;
#pragma unroll
        for (int k = 0; k < 2; ++k) {
            const int e4 = 2 * q + k;
            const float4 x0 = *(const float4*)&bufc[(j0 << 5) + ((e4 ^ s0) << 2)];
            const float4 x1 = *(const float4*)&bufc[(j1 << 5) + ((e4 ^ s1) << 2)];
            const float4 a0 = *(const float4*)&fi[0][dt + (e4 << 2)];
            const float4 a1 = *(const float4*)&fi[1][dt + (e4 << 2)];
            acc00 = fmaf(a0.x, x0.x, acc00); acc00 = fmaf(a0.y, x0.y, acc00);
            acc00 = fmaf(a0.z, x0.z, acc00); acc00 = fmaf(a0.w, x0.w, acc00);
            acc01 = fmaf(a1.x, x0.x, acc01); acc01 = fmaf(a1.y, x0.y, acc01);
            acc01 = fmaf(a1.z, x0.z, acc01); acc01 = fmaf(a1.w, x0.w, acc01);
            acc10 = fmaf(a0.x, x1.x, acc10); acc10 = fmaf(a0.y, x1.y, acc10);
            acc10 = fmaf(a0.z, x1.z, acc10); acc10 = fmaf(a0.w, x1.w, acc10);
            acc11 = fmaf(a1.x, x1.x, acc11); acc11 = fmaf(a1.y, x1.y, acc11);
            acc11 = fmaf(a1.z, x1.z, acc11); acc11 = fmaf(a1.w, x1.w, acc11);
        }
        __builtin_amdgcn_sched_barrier(0);   // keep reads+FMAs before barrier
        __builtin_amdgcn_s_barrier();        // cur safe to overwrite next iter
        cur ^= 1;
    }

    // 4-way partial combine via LDS aliased onto dead buf[0] (tile 7 used
    // buf[1]; trailing barrier above guarantees no wave still reads buf[0]).
    float2* part = (float2*)buf[0];          // part[q*512 + j] = (row0, row1)
    part[(q << 9) + j0] = make_float2(acc00, acc01);
    part[(q << 9) + j1] = make_float2(acc10, acc11);
    __syncthreads();
    const int j = t & (B - 1);               // owned sim column
    const int h = t >> 9;                    // wave-uniform row select
    const float2 p0 = part[(0 << 9) + j];
    const float2 p1 = part[(1 << 9) + j];
    const float2 p2 = part[(2 << 9) + j];
    const float2 p3 = part[(3 << 9) + j];
    const float sv = h ? (p0.y + p1.y + p2.y + p3.y)
                       : (p0.x + p1.x + p2.x + p3.x);

    // num_valid: row j valid iff 2 <= c[l_j] <= B-1 (h=0 half counts)
    {
        bool valid = false;
        if (t < B) { const int c = hist[lbl[t]]; valid = (c >= 2) && (c <= B - 1); }
        const unsigned long long mv = __ballot(valid);
        if (lane == 0) vred[w] = __popcll(mv);
    }

    // ---- hinge phase: both rows concurrently (wave-half per row) ----
    const int r   = h;
    const int i_r = i0 + r;
    const int li  = lbl[i_r];
    {
        const bool active = (j != i_r);
        const bool ispos  = active && (lbl[j] == li);
        const bool isneg  = active && (lbl[j] != li);
        const unsigned long long mp = __ballot(ispos);
        const unsigned long long mn = __ballot(isneg);
        int basep = 0, basen = 0;
        if (lane == 0) {
            basep = atomicAdd(&cnt[r][0], __popcll(mp));
            basen = atomicAdd(&cnt[r][1], __popcll(mn));
        }
        basep = __shfl(basep, 0, 64);
        basen = __shfl(basen, 0, 64);
        const unsigned long long below = (1ull << lane) - 1ull;
        if (ispos) pos_vals[r][basep + __popcll(mp & below)] = sv;
        if (isneg) neg_vals[r][basen + __popcll(mn & below)] = sv;
    }
    __syncthreads();
    const int P = cnt[r][0], N = cnt[r][1];
    if (j < 4) pos_vals[r][P + j] = 1e30f;   // +INF pad -> relu clamps to 0
    __syncthreads();

    // thread owns one neg value; float4 pos reads (broadcast b128)
    const float nv_t = (j < N) ? neg_vals[r][j] : -1e30f;
    float local = 0.f;
    for (int pi = 0; pi < P; pi += 4) {
        const float4 pv = *(const float4*)&pos_vals[r][pi];
        float v;
        v = nv_t - (pv.x - MARGIN); local += (v > 0.f) ? v : 0.f;
        v = nv_t - (pv.y - MARGIN); local += (v > 0.f) ? v : 0.f;
        v = nv_t - (pv.z - MARGIN); local += (v > 0.f) ? v : 0.f;
        v = nv_t - (pv.w - MARGIN); local += (v > 0.f) ? v : 0.f;
    }

    // block reduction: wave64 shuffle, then across 16 waves via LDS
#pragma unroll
    for (int off = 32; off > 0; off >>= 1)
        local += __shfl_down(local, off, 64);
    if (lane == 0) wred[w] = local;
    __syncthreads();
    if (t == 0) {
        float s = 0.f;
        int   nv = 0;
#pragma unroll
        for (int k = 0; k < NWAVES; ++k) { s += wred[k]; nv += vred[k]; }
        const int   clast = hist[lbl[B - 1]];
        const float denom = (float)nv * (float)(clast - 1) * (float)(B - clast);
        atomicAdd(out, (denom > 0.f) ? s / denom : 0.f);
    }
}

extern "C" void kernel_launch(void* const* d_in, const int* in_sizes, int n_in,
                              void* d_out, int out_size, void* d_ws, size_t ws_size,
                              hipStream_t stream) {
    const float* F      = (const float*)d_in[0];   // [512, 256] fp32
    const int*   labels = (const int*)d_in[1];     // [512] int32
    float* out = (float*)d_out;
    (void)d_ws; (void)ws_size;

    fused_loss_kernel<<<NBLOCKS, THREADS, 0, stream>>>(F, labels, out);
}